// Round 3
// baseline (6782.159 us; speedup 1.0000x reference)
//
#include <hip/hip_runtime.h>

#define H 256
#define T_STEPS 128
#define B_BATCH 256

__device__ __forceinline__ float sigmoidf_(float x) { return 1.0f / (1.0f + expf(-x)); }

// ---------------- prep kernels (tiny, once per launch) ----------------

// Weff[i][j] = sum_d W1[d][i] * W2[j][d];  beff[j] = b2[j] + sum_d b1[d]*W2[j][d]
__global__ void prep_weff(const float* __restrict__ W1, const float* __restrict__ W2,
                          const float* __restrict__ b1, const float* __restrict__ b2,
                          float* __restrict__ Weff, float* __restrict__ beff) {
    int i = blockIdx.x, j = threadIdx.x;
    const float* w2row = W2 + j * H;
    float acc = 0.f;
    for (int d = 0; d < H; ++d) acc += W1[d * H + i] * w2row[d];
    Weff[i * H + j] = acc;
    if (i == 0) {
        float bacc = b2[j];
        for (int d = 0; d < H; ++d) bacc += b1[d] * w2row[d];
        beff[j] = bacc;
    }
}

// WhhT[i][r] = W_hh[r][i]   (i in [0,256), r in [0,768))
__global__ void prep_whht(const float* __restrict__ Whh, float* __restrict__ WhhT) {
    int idx = blockIdx.x * blockDim.x + threadIdx.x;  // 196608 total
    int i = idx / 768;
    int r = idx - i * 768;
    WhhT[idx] = Whh[r * H + i];
}

// wo[i] = sum_d Wo1[d][i]*Wo2[d];  bo = bo2[0] + sum_d bo1[d]*Wo2[d]
__global__ void prep_wo(const float* __restrict__ Wo1, const float* __restrict__ Wo2,
                        const float* __restrict__ bo1, const float* __restrict__ bo2,
                        float* __restrict__ wo, float* __restrict__ bo) {
    int i = threadIdx.x;
    float acc = 0.f;
    for (int d = 0; d < H; ++d) acc += Wo1[d * H + i] * Wo2[d];
    wo[i] = acc;
    float p = bo1[i] * Wo2[i];
    __shared__ float red[4];
    for (int off = 32; off > 0; off >>= 1) p += __shfl_down(p, off);
    if ((i & 63) == 0) red[i >> 6] = p;
    __syncthreads();
    if (i == 0) bo[0] = red[0] + red[1] + red[2] + red[3] + bo2[0];
}

// ---------------- main scan: 1 block (1024 thr) per batch row ----------------
// tid = q*256 + j.  q = split-K quarter (owns Weff rows q*64..q*64+63 in VGPRs),
// j = hidden/output index.  q==0 threads own the recurrent state h[j] and do
// the GRU gates.  All math f32 (f16 fails: trajectory divergence, round 2).

__launch_bounds__(1024, 4)
__global__ void ode_rnn_main(
    const float* __restrict__ b_in, const float* __restrict__ m_in,
    const float* __restrict__ trm_in, const float* __restrict__ tem_in,
    const float* __restrict__ h0,
    const float* __restrict__ Weff, const float* __restrict__ beff,
    const float* __restrict__ WhhT,
    const float* __restrict__ W_ih, const float* __restrict__ b_ih,
    const float* __restrict__ b_hh,
    const float* __restrict__ wo, const float* __restrict__ bo_p,
    float* __restrict__ out)
{
    const int tid = threadIdx.x;
    const int bb  = blockIdx.x;
    const int j   = tid & 255;
    const int q   = tid >> 8;

    __shared__ __align__(16) float xs[H];      // broadcast matvec argument / hp
    __shared__ float part[4 * H];              // split-K partials
    __shared__ float gh_lds[768];
    __shared__ float red[4];
    __shared__ float times_s[T_STEPS];
    __shared__ float bv_s[T_STEPS], trm_s[T_STEPS], tem_s[T_STEPS], m_s[T_STEPS];

    // Weff quarter-columns into registers: 64 f32 (coalesced across j)
    float wreg[64];
    #pragma unroll
    for (int p = 0; p < 64; ++p) wreg[p] = Weff[(q * 64 + p) * H + j];

    if (tid < T_STEPS) {
        times_s[tid] = b_in[2 * tid];          // times identical across batch
        int bt = bb * T_STEPS + tid;
        bv_s[tid]  = b_in[2 * bt + 1];
        trm_s[tid] = trm_in[bt];
        tem_s[tid] = tem_in[bt];
        m_s[tid]   = m_in[bt];
    }

    float h = 0.f, be = 0.f;
    float bihr = 0, bihz = 0, bihn = 0, bhhr = 0, bhhz = 0, bhhn = 0;
    float wihr = 0, wihz = 0, wihn = 0, woj = 0;
    const float bo = bo_p[0];
    if (q == 0) {
        h = h0[bb * H + j];
        be = beff[j];
        bihr = b_ih[j]; bihz = b_ih[H + j]; bihn = b_ih[2 * H + j];
        bhhr = b_hh[j]; bhhz = b_hh[H + j]; bhhn = b_hh[2 * H + j];
        wihr = W_ih[j]; wihz = W_ih[H + j]; wihn = W_ih[2 * H + j];
    }
    if (q == 3) woj = wo[j];
    __syncthreads();

    // q==0 publishes the matvec argument; everyone barriers.
    // (prev readers of xs finished before the PREVIOUS barrier, so the
    //  pre-barrier write is safe; see barrier analysis in session notes)
    #define WRITE_XS(VAL) do {                                     \
        float v_ = (VAL);                                          \
        if (q == 0) xs[j] = v_;                                    \
        __syncthreads();                                           \
    } while (0)

    #define PARTIALS() do {                                        \
        float a0_ = 0.f, a1_ = 0.f, a2_ = 0.f, a3_ = 0.f;          \
        const float* xp_ = xs + q * 64;                            \
        _Pragma("unroll")                                          \
        for (int p = 0; p < 64; p += 8) {                          \
            float4 xa_ = *(const float4*)(xp_ + p);                \
            float4 xb_ = *(const float4*)(xp_ + p + 4);            \
            a0_ = fmaf(xa_.x, wreg[p + 0], a0_);                   \
            a1_ = fmaf(xa_.y, wreg[p + 1], a1_);                   \
            a2_ = fmaf(xa_.z, wreg[p + 2], a2_);                   \
            a3_ = fmaf(xa_.w, wreg[p + 3], a3_);                   \
            a0_ = fmaf(xb_.x, wreg[p + 4], a0_);                   \
            a1_ = fmaf(xb_.y, wreg[p + 5], a1_);                   \
            a2_ = fmaf(xb_.z, wreg[p + 6], a2_);                   \
            a3_ = fmaf(xb_.w, wreg[p + 7], a3_);                   \
        }                                                          \
        part[q * 256 + j] = (a0_ + a1_) + (a2_ + a3_);             \
        __syncthreads();                                           \
    } while (0)

    #define COMBINE(K) do {                                        \
        if (q == 0)                                                \
            K = tanhf(be + part[j] + part[256 + j] +               \
                      part[512 + j] + part[768 + j]);              \
    } while (0)

    float tprev = 0.f;
    for (int t = 0; t < T_STEPS; ++t) {
        float t1 = times_s[t];
        float dt = (t1 - tprev) * 0.5f;   // per-substep dt (N_SUB=2)
        tprev = t1;

        #pragma unroll 1
        for (int s = 0; s < 2; ++s) {
            float k1 = 0, k2 = 0, k3 = 0, k4 = 0;
            WRITE_XS(h);                       PARTIALS(); COMBINE(k1);
            WRITE_XS(fmaf(0.5f * dt, k1, h));  PARTIALS(); COMBINE(k2);
            WRITE_XS(fmaf(0.5f * dt, k2, h));  PARTIALS(); COMBINE(k3);
            WRITE_XS(fmaf(dt, k3, h));         PARTIALS(); COMBINE(k4);
            if (q == 0) h = fmaf(dt * (1.f / 6.f), k1 + 2.f * (k2 + k3) + k4, h);
        }

        // stage hp for the gh matvec + out head
        if (q == 0) xs[j] = h;
        __syncthreads();

        // gh = hp @ W_hh^T (threads 0..767, one row each, coalesced across r)
        // || out-head dot (waves 12..15)
        if (tid < 768) {
            float g0 = 0.f, g1 = 0.f, g2 = 0.f, g3 = 0.f;
            const float* wr = WhhT + tid;
            #pragma unroll 8
            for (int i = 0; i < H; i += 4) {
                float4 xv = *(const float4*)(xs + i);
                g0 = fmaf(xv.x, wr[(i + 0) * 768], g0);
                g1 = fmaf(xv.y, wr[(i + 1) * 768], g1);
                g2 = fmaf(xv.z, wr[(i + 2) * 768], g2);
                g3 = fmaf(xv.w, wr[(i + 3) * 768], g3);
            }
            gh_lds[tid] = (g0 + g1) + (g2 + g3);
        } else {
            float p = xs[j] * woj;
            #pragma unroll
            for (int off = 32; off > 0; off >>= 1) p += __shfl_down(p, off);
            if ((tid & 63) == 0) red[(tid - 768) >> 6] = p;
        }
        __syncthreads();

        // gates (q==0 threads own the state)
        if (q == 0) {
            float outv = tanhf(red[0] + red[1] + red[2] + red[3] + bo);
            float bv = bv_s[t], trm = trm_s[t], tem = tem_s[t], mv = m_s[t];
            float ghr = gh_lds[j] + bhhr;
            float ghz = gh_lds[256 + j] + bhhz;
            float ghn = gh_lds[512 + j] + bhhn;
            float x1v = bv * trm, x2v = outv * tem;

            float r1 = sigmoidf_(fmaf(x1v, wihr, bihr) + ghr);
            float z1 = sigmoidf_(fmaf(x1v, wihz, bihz) + ghz);
            float n1 = tanhf(fmaf(x1v, wihn, bihn) + r1 * ghn);
            float h1 = (1.f - z1) * n1 + z1 * h;

            float r2 = sigmoidf_(fmaf(x2v, wihr, bihr) + ghr);
            float z2 = sigmoidf_(fmaf(x2v, wihz, bihz) + ghz);
            float n2 = tanhf(fmaf(x2v, wihn, bihn) + r2 * ghn);
            float h2 = (1.f - z2) * n2 + z2 * h;

            if (tid == 0) out[bb * T_STEPS + t] = outv;
            h = trm * h1 + tem * h2 + (1.f - mv) * h;
        }
    }
    #undef WRITE_XS
    #undef PARTIALS
    #undef COMBINE
}

// ---------------- launcher ----------------

extern "C" void kernel_launch(void* const* d_in, const int* in_sizes, int n_in,
                              void* d_out, int out_size, void* d_ws, size_t ws_size,
                              hipStream_t stream) {
    const float* b_in = (const float*)d_in[0];
    const float* m_in = (const float*)d_in[1];
    const float* trm  = (const float*)d_in[2];
    const float* tem  = (const float*)d_in[3];
    const float* h0   = (const float*)d_in[4];
    const float* W1   = (const float*)d_in[5];
    const float* b1   = (const float*)d_in[6];
    const float* W2   = (const float*)d_in[7];
    const float* b2   = (const float*)d_in[8];
    const float* W_ih = (const float*)d_in[9];
    const float* W_hh = (const float*)d_in[10];
    const float* b_ih = (const float*)d_in[11];
    const float* b_hh = (const float*)d_in[12];
    const float* Wo1  = (const float*)d_in[13];
    const float* bo1  = (const float*)d_in[14];
    const float* Wo2  = (const float*)d_in[15];
    const float* bo2  = (const float*)d_in[16];

    float* ws   = (float*)d_ws;
    float* Weff = ws;             // 65536
    float* beff = Weff + 65536;   // 256
    float* WhhT = beff + 256;     // 196608
    float* wo   = WhhT + 196608;  // 256
    float* bo   = wo + 256;       // 1

    prep_weff<<<256, 256, 0, stream>>>(W1, W2, b1, b2, Weff, beff);
    prep_whht<<<192, 1024, 0, stream>>>(W_hh, WhhT);
    prep_wo<<<1, 256, 0, stream>>>(Wo1, Wo2, bo1, bo2, wo, bo);

    ode_rnn_main<<<B_BATCH, 1024, 0, stream>>>(b_in, m_in, trm, tem, h0,
                                               Weff, beff, WhhT,
                                               W_ih, b_ih, b_hh, wo, bo,
                                               (float*)d_out);
}

// Round 4
// 2832.950 us; speedup vs baseline: 2.3940x; 2.3940x over previous
//
#include <hip/hip_runtime.h>

#define H 256
#define T_STEPS 128
#define B_BATCH 256
#define XPAD 68   // padded quarter stride (words): banks (68*q+p)%32 distinct per q

__device__ __forceinline__ float sigmoidf_(float x) { return 1.0f / (1.0f + expf(-x)); }

// ---------------- prep kernels (tiny, once per launch) ----------------

// Weff[i][j] = sum_d W1[d][i] * W2[j][d];  beff[j] = b2[j] + sum_d b1[d]*W2[j][d]
__global__ void prep_weff(const float* __restrict__ W1, const float* __restrict__ W2,
                          const float* __restrict__ b1, const float* __restrict__ b2,
                          float* __restrict__ Weff, float* __restrict__ beff) {
    int i = blockIdx.x, j = threadIdx.x;
    const float* w2row = W2 + j * H;
    float acc = 0.f;
    for (int d = 0; d < H; ++d) acc += W1[d * H + i] * w2row[d];
    Weff[i * H + j] = acc;
    if (i == 0) {
        float bacc = b2[j];
        for (int d = 0; d < H; ++d) bacc += b1[d] * w2row[d];
        beff[j] = bacc;
    }
}

// WhhT[i][r] = W_hh[r][i]   (i in [0,256), r in [0,768))
__global__ void prep_whht(const float* __restrict__ Whh, float* __restrict__ WhhT) {
    int idx = blockIdx.x * blockDim.x + threadIdx.x;  // 196608 total
    int i = idx / 768;
    int r = idx - i * 768;
    WhhT[idx] = Whh[r * H + i];
}

// wo[i] = sum_d Wo1[d][i]*Wo2[d];  bo = bo2[0] + sum_d bo1[d]*Wo2[d]
__global__ void prep_wo(const float* __restrict__ Wo1, const float* __restrict__ Wo2,
                        const float* __restrict__ bo1, const float* __restrict__ bo2,
                        float* __restrict__ wo, float* __restrict__ bo) {
    int i = threadIdx.x;
    float acc = 0.f;
    for (int d = 0; d < H; ++d) acc += Wo1[d * H + i] * Wo2[d];
    wo[i] = acc;
    float p = bo1[i] * Wo2[i];
    __shared__ float red[4];
    for (int off = 32; off > 0; off >>= 1) p += __shfl_down(p, off);
    if ((i & 63) == 0) red[i >> 6] = p;
    __syncthreads();
    if (i == 0) bo[0] = red[0] + red[1] + red[2] + red[3] + bo2[0];
}

// ---------------- main scan: 1 block (1024 thr) per batch row ----------------
// tid = 4*j + q.  j = column (hidden index), q = split-K quarter.
// Each thread holds 64 Weff entries (rows q*64..q*64+63 of column j) in VGPRs.
// The 4 partials of a column live in one quad -> combine via 2x shfl_xor
// (no LDS, no barrier).  h and the gates are maintained redundantly in all
// 4 quad lanes (bit-identical).  xs is double-buffered so each eval needs
// exactly ONE barrier.  All math f32 (f16 diverges, round 2).

__global__ __attribute__((amdgpu_flat_work_group_size(1024, 1024),
                          amdgpu_waves_per_eu(4, 4)))
void ode_rnn_main(
    const float* __restrict__ b_in, const float* __restrict__ m_in,
    const float* __restrict__ trm_in, const float* __restrict__ tem_in,
    const float* __restrict__ h0,
    const float* __restrict__ Weff, const float* __restrict__ beff,
    const float* __restrict__ WhhT,
    const float* __restrict__ W_ih, const float* __restrict__ b_ih,
    const float* __restrict__ b_hh,
    const float* __restrict__ wo, const float* __restrict__ bo_p,
    float* __restrict__ out)
{
    const int tid = threadIdx.x;
    const int bb  = blockIdx.x;
    const int j   = tid >> 2;    // column 0..255
    const int q   = tid & 3;     // split-K quarter

    __shared__ __align__(16) float xsb[2][4 * XPAD];  // double-buffered matvec arg
    __shared__ __align__(16) float xsf[H];            // hp (linear, for gh/out head)
    __shared__ float gh_lds[768];
    __shared__ float red[4];
    __shared__ float times_s[T_STEPS];
    __shared__ float bv_s[T_STEPS], trm_s[T_STEPS], tem_s[T_STEPS], m_s[T_STEPS];

    // 64 Weff weights per thread (rows q*64..+63 of column j)
    float wreg[64];
    #pragma unroll
    for (int p = 0; p < 64; ++p) wreg[p] = Weff[(q * 64 + p) * H + j];

    if (tid < T_STEPS) {
        times_s[tid] = b_in[2 * tid];          // times identical across batch
        int bt = bb * T_STEPS + tid;
        bv_s[tid]  = b_in[2 * bt + 1];
        trm_s[tid] = trm_in[bt];
        tem_s[tid] = tem_in[bt];
        m_s[tid]   = m_in[bt];
    }

    // per-column constants, replicated in all 4 quad lanes
    float h = h0[bb * H + j];
    const float be   = beff[j];
    const float bihr = b_ih[j], bihz = b_ih[H + j], bihn = b_ih[2 * H + j];
    const float bhhr = b_hh[j], bhhz = b_hh[H + j], bhhn = b_hh[2 * H + j];
    const float wihr = W_ih[j], wihz = W_ih[H + j], wihn = W_ih[2 * H + j];
    const float bo   = bo_p[0];
    const float wo_t = (tid >= 768) ? wo[tid - 768] : 0.f;

    const int myidx = j + 4 * (j >> 6);   // == (j>>6)*XPAD + (j&63)

    if (q == 0) xsb[0][myidx] = h;        // initial publish (step 0 reads buf 0)
    __syncthreads();

    // one eval: read quarter from xsb[cur], 64 FMA, quad-combine, tanh
    #define EVAL(KOUT) do {                                        \
        const float* xp_ = &xsb[cur][q * XPAD];                    \
        float a0_ = 0.f, a1_ = 0.f, a2_ = 0.f, a3_ = 0.f;          \
        _Pragma("unroll")                                          \
        for (int p = 0; p < 64; p += 8) {                          \
            float4 xa_ = *(const float4*)(xp_ + p);                \
            float4 xb_ = *(const float4*)(xp_ + p + 4);            \
            a0_ = fmaf(xa_.x, wreg[p + 0], a0_);                   \
            a1_ = fmaf(xa_.y, wreg[p + 1], a1_);                   \
            a2_ = fmaf(xa_.z, wreg[p + 2], a2_);                   \
            a3_ = fmaf(xa_.w, wreg[p + 3], a3_);                   \
            a0_ = fmaf(xb_.x, wreg[p + 4], a0_);                   \
            a1_ = fmaf(xb_.y, wreg[p + 5], a1_);                   \
            a2_ = fmaf(xb_.z, wreg[p + 6], a2_);                   \
            a3_ = fmaf(xb_.w, wreg[p + 7], a3_);                   \
        }                                                          \
        float s_ = (a0_ + a1_) + (a2_ + a3_);                      \
        s_ += __shfl_xor(s_, 1);                                   \
        s_ += __shfl_xor(s_, 2);                                   \
        KOUT = tanhf(be + s_);                                     \
    } while (0)

    // publish next matvec arg into the other buffer; one barrier; flip
    #define PUBLISH(V) do {                                        \
        if (q == 0) xsb[cur ^ 1][myidx] = (V);                     \
        __syncthreads();                                           \
        cur ^= 1;                                                  \
    } while (0)

    float tprev = 0.f;
    for (int t = 0; t < T_STEPS; ++t) {
        float t1 = times_s[t];
        float dt = (t1 - tprev) * 0.5f;   // per-substep dt (N_SUB=2)
        tprev = t1;

        int cur = 0;
        float k1, k2, k3, k4;
        #pragma unroll 1
        for (int s = 0; s < 2; ++s) {
            EVAL(k1); PUBLISH(fmaf(0.5f * dt, k1, h));
            EVAL(k2); PUBLISH(fmaf(0.5f * dt, k2, h));
            EVAL(k3); PUBLISH(fmaf(dt, k3, h));
            EVAL(k4);
            h = fmaf(dt * (1.f / 6.f), k1 + 2.f * (k2 + k3) + k4, h);
            if (s == 0) PUBLISH(h);   // substep-2 k1 reads h
        }

        // stage hp (linear) for gh + out head
        if (q == 0) xsf[j] = h;
        __syncthreads();

        // gh = hp @ W_hh^T (threads 0..767, coalesced across r)
        // || out-head dot (waves 12..15)
        if (tid < 768) {
            float g0 = 0.f, g1 = 0.f, g2 = 0.f, g3 = 0.f;
            const float* wr = WhhT + tid;
            #pragma unroll 8
            for (int i = 0; i < H; i += 4) {
                float4 xv = *(const float4*)(xsf + i);
                g0 = fmaf(xv.x, wr[(i + 0) * 768], g0);
                g1 = fmaf(xv.y, wr[(i + 1) * 768], g1);
                g2 = fmaf(xv.z, wr[(i + 2) * 768], g2);
                g3 = fmaf(xv.w, wr[(i + 3) * 768], g3);
            }
            gh_lds[tid] = (g0 + g1) + (g2 + g3);
        } else {
            float p = xsf[tid - 768] * wo_t;
            #pragma unroll
            for (int off = 32; off > 0; off >>= 1) p += __shfl_down(p, off);
            if ((tid & 63) == 0) red[(tid - 768) >> 6] = p;
        }
        __syncthreads();

        // gates: ALL threads compute for their j (quad-redundant, bit-identical)
        {
            float outv = tanhf(red[0] + red[1] + red[2] + red[3] + bo);
            float bv = bv_s[t], trm = trm_s[t], tem = tem_s[t], mv = m_s[t];
            float ghr = gh_lds[j] + bhhr;
            float ghz = gh_lds[256 + j] + bhhz;
            float ghn = gh_lds[512 + j] + bhhn;
            float x1v = bv * trm, x2v = outv * tem;

            float r1 = sigmoidf_(fmaf(x1v, wihr, bihr) + ghr);
            float z1 = sigmoidf_(fmaf(x1v, wihz, bihz) + ghz);
            float n1 = tanhf(fmaf(x1v, wihn, bihn) + r1 * ghn);
            float h1 = (1.f - z1) * n1 + z1 * h;

            float r2 = sigmoidf_(fmaf(x2v, wihr, bihr) + ghr);
            float z2 = sigmoidf_(fmaf(x2v, wihz, bihz) + ghz);
            float n2 = tanhf(fmaf(x2v, wihn, bihn) + r2 * ghn);
            float h2 = (1.f - z2) * n2 + z2 * h;

            if (tid == 0) out[bb * T_STEPS + t] = outv;
            h = trm * h1 + tem * h2 + (1.f - mv) * h;
        }

        // publish h_new for next step's first eval (reads buf 0)
        if (q == 0) xsb[0][myidx] = h;
        __syncthreads();
    }
    #undef EVAL
    #undef PUBLISH
}

// ---------------- launcher ----------------

extern "C" void kernel_launch(void* const* d_in, const int* in_sizes, int n_in,
                              void* d_out, int out_size, void* d_ws, size_t ws_size,
                              hipStream_t stream) {
    const float* b_in = (const float*)d_in[0];
    const float* m_in = (const float*)d_in[1];
    const float* trm  = (const float*)d_in[2];
    const float* tem  = (const float*)d_in[3];
    const float* h0   = (const float*)d_in[4];
    const float* W1   = (const float*)d_in[5];
    const float* b1   = (const float*)d_in[6];
    const float* W2   = (const float*)d_in[7];
    const float* b2   = (const float*)d_in[8];
    const float* W_ih = (const float*)d_in[9];
    const float* W_hh = (const float*)d_in[10];
    const float* b_ih = (const float*)d_in[11];
    const float* b_hh = (const float*)d_in[12];
    const float* Wo1  = (const float*)d_in[13];
    const float* bo1  = (const float*)d_in[14];
    const float* Wo2  = (const float*)d_in[15];
    const float* bo2  = (const float*)d_in[16];

    float* ws   = (float*)d_ws;
    float* Weff = ws;             // 65536
    float* beff = Weff + 65536;   // 256
    float* WhhT = beff + 256;     // 196608
    float* wo   = WhhT + 196608;  // 256
    float* bo   = wo + 256;       // 1

    prep_weff<<<256, 256, 0, stream>>>(W1, W2, b1, b2, Weff, beff);
    prep_whht<<<192, 1024, 0, stream>>>(W_hh, WhhT);
    prep_wo<<<1, 256, 0, stream>>>(Wo1, Wo2, bo1, bo2, wo, bo);

    ode_rnn_main<<<B_BATCH, 1024, 0, stream>>>(b_in, m_in, trm, tem, h0,
                                               Weff, beff, WhhT,
                                               W_ih, b_ih, b_hh, wo, bo,
                                               (float*)d_out);
}

// Round 5
// 2286.889 us; speedup vs baseline: 2.9657x; 1.2388x over previous
//
#include <hip/hip_runtime.h>

#define H 256
#define T_STEPS 128
#define B_BATCH 256
#define XPAD 68        // padded quarter stride (words)
#define I_LDS 44       // WhhT rows [0,44) persistent in LDS (44*768*4B = 132KB)

__device__ __forceinline__ float sigmoidf_(float x) { return 1.0f / (1.0f + expf(-x)); }

// ---------------- prep kernels (tiny, once per launch) ----------------

// Weff[i][j] = sum_d W1[d][i] * W2[j][d];  beff[j] = b2[j] + sum_d b1[d]*W2[j][d]
__global__ void prep_weff(const float* __restrict__ W1, const float* __restrict__ W2,
                          const float* __restrict__ b1, const float* __restrict__ b2,
                          float* __restrict__ Weff, float* __restrict__ beff) {
    int i = blockIdx.x, j = threadIdx.x;
    const float* w2row = W2 + j * H;
    float acc = 0.f;
    for (int d = 0; d < H; ++d) acc += W1[d * H + i] * w2row[d];
    Weff[i * H + j] = acc;
    if (i == 0) {
        float bacc = b2[j];
        for (int d = 0; d < H; ++d) bacc += b1[d] * w2row[d];
        beff[j] = bacc;
    }
}

// WhhT[i][r] = W_hh[r][i]   (i in [0,256), r in [0,768))
__global__ void prep_whht(const float* __restrict__ Whh, float* __restrict__ WhhT) {
    int idx = blockIdx.x * blockDim.x + threadIdx.x;  // 196608 total
    int i = idx / 768;
    int r = idx - i * 768;
    WhhT[idx] = Whh[r * H + i];
}

// wo[i] = sum_d Wo1[d][i]*Wo2[d];  bo = bo2[0] + sum_d bo1[d]*Wo2[d]
__global__ void prep_wo(const float* __restrict__ Wo1, const float* __restrict__ Wo2,
                        const float* __restrict__ bo1, const float* __restrict__ bo2,
                        float* __restrict__ wo, float* __restrict__ bo) {
    int i = threadIdx.x;
    float acc = 0.f;
    for (int d = 0; d < H; ++d) acc += Wo1[d * H + i] * Wo2[d];
    wo[i] = acc;
    float p = bo1[i] * Wo2[i];
    __shared__ float red[4];
    for (int off = 32; off > 0; off >>= 1) p += __shfl_down(p, off);
    if ((i & 63) == 0) red[i >> 6] = p;
    __syncthreads();
    if (i == 0) bo[0] = red[0] + red[1] + red[2] + red[3] + bo2[0];
}

// ---------------- main scan: 1 block (1024 thr) per batch row ----------------
// tid = 4*j + q.  j = column, q = split-K quarter.  Each thread holds 64 Weff
// entries in VGPRs, asm-pinned so the allocator can neither spill NOR
// rematerialize them (round 3 spilled; round 4 rematerialized -> L2-bound).
// WhhT rows [0,I_LDS) live persistently in LDS: removes 17% of the gh L2
// stream AND pushes LDS>80KB so only 1 block/CU fits -> the register
// allocator's 2-blocks/CU squeeze (the round-4 pathology) is impossible.
// All math f32 (f16 diverges, round 2).

__global__ __attribute__((amdgpu_flat_work_group_size(1024, 1024),
                          amdgpu_waves_per_eu(4, 4)))
void ode_rnn_main(
    const float* __restrict__ b_in, const float* __restrict__ m_in,
    const float* __restrict__ trm_in, const float* __restrict__ tem_in,
    const float* __restrict__ h0,
    const float* __restrict__ Weff, const float* __restrict__ beff,
    const float* __restrict__ WhhT,
    const float* __restrict__ W_ih, const float* __restrict__ b_ih,
    const float* __restrict__ b_hh,
    const float* __restrict__ wo, const float* __restrict__ bo_p,
    float* __restrict__ out)
{
    const int tid = threadIdx.x;
    const int bb  = blockIdx.x;
    const int j   = tid >> 2;    // column 0..255
    const int q   = tid & 3;     // split-K quarter

    __shared__ float whh_lds[I_LDS * 768];            // 132 KB persistent
    __shared__ __align__(16) float xsb[2][4 * XPAD];  // double-buffered matvec arg
    __shared__ __align__(16) float xsf[H];            // hp (linear)
    __shared__ float gh_lds[768];
    __shared__ float red[4];
    __shared__ float times_s[T_STEPS];
    __shared__ float bv_s[T_STEPS], trm_s[T_STEPS], tem_s[T_STEPS], m_s[T_STEPS];

    // 64 Weff weights per thread (rows q*64..+63 of column j), pinned in VGPRs
    float wreg[64];
    #pragma unroll
    for (int p = 0; p < 64; ++p) wreg[p] = Weff[(q * 64 + p) * H + j];
    #pragma unroll
    for (int p = 0; p < 64; ++p) asm volatile("" : "+v"(wreg[p]));

    // stage WhhT rows [0, I_LDS) into LDS (33 coalesced iters/thread)
    for (int k = tid; k < I_LDS * 768; k += 1024) whh_lds[k] = WhhT[k];

    if (tid < T_STEPS) {
        times_s[tid] = b_in[2 * tid];          // times identical across batch
        int bt = bb * T_STEPS + tid;
        bv_s[tid]  = b_in[2 * bt + 1];
        trm_s[tid] = trm_in[bt];
        tem_s[tid] = tem_in[bt];
        m_s[tid]   = m_in[bt];
    }

    // per-column constants, replicated in all 4 quad lanes
    float h = h0[bb * H + j];
    const float be   = beff[j];
    const float bihr = b_ih[j], bihz = b_ih[H + j], bihn = b_ih[2 * H + j];
    const float bhhr = b_hh[j], bhhz = b_hh[H + j], bhhn = b_hh[2 * H + j];
    const float wihr = W_ih[j], wihz = W_ih[H + j], wihn = W_ih[2 * H + j];
    const float bo   = bo_p[0];
    const float wo_t = (tid >= 768) ? wo[tid - 768] : 0.f;

    const int myidx = j + 4 * (j >> 6);   // == (j>>6)*XPAD + (j&63)

    if (q == 0) xsb[0][myidx] = h;        // initial publish (step 0 reads buf 0)
    __syncthreads();

    // one eval: read quarter from xsb[cur], 64 FMA, quad-combine, tanh
    #define EVAL(KOUT) do {                                        \
        const float* xp_ = &xsb[cur][q * XPAD];                    \
        float a0_ = 0.f, a1_ = 0.f, a2_ = 0.f, a3_ = 0.f;          \
        _Pragma("unroll")                                          \
        for (int p = 0; p < 64; p += 8) {                          \
            float4 xa_ = *(const float4*)(xp_ + p);                \
            float4 xb_ = *(const float4*)(xp_ + p + 4);            \
            a0_ = fmaf(xa_.x, wreg[p + 0], a0_);                   \
            a1_ = fmaf(xa_.y, wreg[p + 1], a1_);                   \
            a2_ = fmaf(xa_.z, wreg[p + 2], a2_);                   \
            a3_ = fmaf(xa_.w, wreg[p + 3], a3_);                   \
            a0_ = fmaf(xb_.x, wreg[p + 4], a0_);                   \
            a1_ = fmaf(xb_.y, wreg[p + 5], a1_);                   \
            a2_ = fmaf(xb_.z, wreg[p + 6], a2_);                   \
            a3_ = fmaf(xb_.w, wreg[p + 7], a3_);                   \
        }                                                          \
        float s_ = (a0_ + a1_) + (a2_ + a3_);                      \
        s_ += __shfl_xor(s_, 1);                                   \
        s_ += __shfl_xor(s_, 2);                                   \
        KOUT = tanhf(be + s_);                                     \
    } while (0)

    #define PUBLISH(V) do {                                        \
        if (q == 0) xsb[cur ^ 1][myidx] = (V);                     \
        __syncthreads();                                           \
        cur ^= 1;                                                  \
    } while (0)

    float tprev = 0.f;
    for (int t = 0; t < T_STEPS; ++t) {
        float t1 = times_s[t];
        float dt = (t1 - tprev) * 0.5f;   // per-substep dt (N_SUB=2)
        tprev = t1;

        int cur = 0;
        float k1, k2, k3, k4;
        #pragma unroll 1
        for (int s = 0; s < 2; ++s) {
            EVAL(k1); PUBLISH(fmaf(0.5f * dt, k1, h));
            EVAL(k2); PUBLISH(fmaf(0.5f * dt, k2, h));
            EVAL(k3); PUBLISH(fmaf(dt, k3, h));
            EVAL(k4);
            h = fmaf(dt * (1.f / 6.f), k1 + 2.f * (k2 + k3) + k4, h);
            if (s == 0) PUBLISH(h);   // substep-2 k1 reads h
        }

        // stage hp (linear) for gh + out head
        if (q == 0) xsf[j] = h;
        __syncthreads();

        // gh = hp @ W_hh^T: rows [0,I_LDS) from LDS, rest streamed from L2.
        // || out-head dot (waves 12..15)
        if (tid < 768) {
            float g0 = 0.f, g1 = 0.f, g2 = 0.f, g3 = 0.f;
            const float* wl = whh_lds + tid;
            #pragma unroll 4
            for (int i = 0; i < I_LDS; i += 4) {
                float4 xv = *(const float4*)(xsf + i);
                g0 = fmaf(xv.x, wl[(i + 0) * 768], g0);
                g1 = fmaf(xv.y, wl[(i + 1) * 768], g1);
                g2 = fmaf(xv.z, wl[(i + 2) * 768], g2);
                g3 = fmaf(xv.w, wl[(i + 3) * 768], g3);
            }
            const float* wr = WhhT + I_LDS * 768 + tid;
            #pragma unroll 8
            for (int i = 0; i < H - I_LDS; i += 4) {
                float4 xv = *(const float4*)(xsf + I_LDS + i);
                g0 = fmaf(xv.x, wr[(i + 0) * 768], g0);
                g1 = fmaf(xv.y, wr[(i + 1) * 768], g1);
                g2 = fmaf(xv.z, wr[(i + 2) * 768], g2);
                g3 = fmaf(xv.w, wr[(i + 3) * 768], g3);
            }
            gh_lds[tid] = (g0 + g1) + (g2 + g3);
        } else {
            float p = xsf[tid - 768] * wo_t;
            #pragma unroll
            for (int off = 32; off > 0; off >>= 1) p += __shfl_down(p, off);
            if ((tid & 63) == 0) red[(tid - 768) >> 6] = p;
        }
        __syncthreads();

        // gates: ALL threads compute for their j (quad-redundant, bit-identical)
        {
            float outv = tanhf(red[0] + red[1] + red[2] + red[3] + bo);
            float bv = bv_s[t], trm = trm_s[t], tem = tem_s[t], mv = m_s[t];
            float ghr = gh_lds[j] + bhhr;
            float ghz = gh_lds[256 + j] + bhhz;
            float ghn = gh_lds[512 + j] + bhhn;
            float x1v = bv * trm, x2v = outv * tem;

            float r1 = sigmoidf_(fmaf(x1v, wihr, bihr) + ghr);
            float z1 = sigmoidf_(fmaf(x1v, wihz, bihz) + ghz);
            float n1 = tanhf(fmaf(x1v, wihn, bihn) + r1 * ghn);
            float h1 = (1.f - z1) * n1 + z1 * h;

            float r2 = sigmoidf_(fmaf(x2v, wihr, bihr) + ghr);
            float z2 = sigmoidf_(fmaf(x2v, wihz, bihz) + ghz);
            float n2 = tanhf(fmaf(x2v, wihn, bihn) + r2 * ghn);
            float h2 = (1.f - z2) * n2 + z2 * h;

            if (tid == 0) out[bb * T_STEPS + t] = outv;
            h = trm * h1 + tem * h2 + (1.f - mv) * h;
        }

        // publish h_new for next step's first eval (reads buf 0)
        if (q == 0) xsb[0][myidx] = h;
        __syncthreads();
    }
    #undef EVAL
    #undef PUBLISH
}

// ---------------- launcher ----------------

extern "C" void kernel_launch(void* const* d_in, const int* in_sizes, int n_in,
                              void* d_out, int out_size, void* d_ws, size_t ws_size,
                              hipStream_t stream) {
    const float* b_in = (const float*)d_in[0];
    const float* m_in = (const float*)d_in[1];
    const float* trm  = (const float*)d_in[2];
    const float* tem  = (const float*)d_in[3];
    const float* h0   = (const float*)d_in[4];
    const float* W1   = (const float*)d_in[5];
    const float* b1   = (const float*)d_in[6];
    const float* W2   = (const float*)d_in[7];
    const float* b2   = (const float*)d_in[8];
    const float* W_ih = (const float*)d_in[9];
    const float* W_hh = (const float*)d_in[10];
    const float* b_ih = (const float*)d_in[11];
    const float* b_hh = (const float*)d_in[12];
    const float* Wo1  = (const float*)d_in[13];
    const float* bo1  = (const float*)d_in[14];
    const float* Wo2  = (const float*)d_in[15];
    const float* bo2  = (const float*)d_in[16];

    float* ws   = (float*)d_ws;
    float* Weff = ws;             // 65536
    float* beff = Weff + 65536;   // 256
    float* WhhT = beff + 256;     // 196608
    float* wo   = WhhT + 196608;  // 256
    float* bo   = wo + 256;       // 1

    prep_weff<<<256, 256, 0, stream>>>(W1, W2, b1, b2, Weff, beff);
    prep_whht<<<192, 1024, 0, stream>>>(W_hh, WhhT);
    prep_wo<<<1, 256, 0, stream>>>(Wo1, Wo2, bo1, bo2, wo, bo);

    ode_rnn_main<<<B_BATCH, 1024, 0, stream>>>(b_in, m_in, trm, tem, h0,
                                               Weff, beff, WhhT,
                                               W_ih, b_ih, b_hh, wo, bo,
                                               (float*)d_out);
}